// Round 2
// baseline (2382.166 us; speedup 1.0000x reference)
//
#include <hip/hip_runtime.h>
#include <hip/hip_bf16.h>

typedef __hip_bfloat16 bf16;

#define B_    64
#define HFS   56
#define CIN   96
#define NQ    785
#define NK    197
#define QW    28
#define KW    14
#define NTOT  3137   // 56*56+1

__device__ __forceinline__ float b2f(bf16 x) { return __bfloat162float(x); }
__device__ __forceinline__ bf16  f2b(float x) { return __float2bfloat16(x); }

// ---------------------------------------------------------------------------
// Kernel 1: depthwise 3x3 pool conv (stride 2 q / stride 4 kv) + LayerNorm
// + fused projection (x @ W + b), split into 2 heads.
// One wave (64 lanes) per output token; lane covers channels {lane, lane+64}.
// After LN, the token's 96-vector is staged in LDS and each lane computes
// 3 of the 192 projection outputs (coalesced W column reads).
// ---------------------------------------------------------------------------
__global__ __launch_bounds__(256) void pool_ln_proj_kernel(
    const float* __restrict__ hs,
    const float* __restrict__ cwq, const float* __restrict__ cwk, const float* __restrict__ cwv,
    const float* __restrict__ gq, const float* __restrict__ betaq,
    const float* __restrict__ gk, const float* __restrict__ betak,
    const float* __restrict__ gv, const float* __restrict__ betav,
    const float* __restrict__ Wq, const float* __restrict__ bq,
    const float* __restrict__ Wk, const float* __restrict__ bk,
    const float* __restrict__ Wv, const float* __restrict__ bv,
    float* __restrict__ qp, float* __restrict__ kp, float* __restrict__ vp)
{
    __shared__ float row_s[4][CIN];

    int wid  = threadIdx.x >> 6;
    int lane = threadIdx.x & 63;
    int gid  = blockIdx.x * 4 + wid;          // token slot; 64*1179 total exactly
    int b = gid / 1179;
    int t = gid % 1179;

    const float *wgt, *g, *beta, *W, *bias;
    float* outb;                               // base of [b][h][n][96] tensor
    int tok, ow, stride, ntok;
    if (t < NQ) {
        tok = t; ow = QW; stride = 2; ntok = NQ;
        wgt = cwq; g = gq; beta = betaq; W = Wq; bias = bq; outb = qp;
    } else if (t < NQ + NK) {
        tok = t - NQ; ow = KW; stride = 4; ntok = NK;
        wgt = cwk; g = gk; beta = betak; W = Wk; bias = bk; outb = kp;
    } else {
        tok = t - NQ - NK; ow = KW; stride = 4; ntok = NK;
        wgt = cwv; g = gv; beta = betav; W = Wv; bias = bv; outb = vp;
    }

    int c0 = lane, c1 = lane + 64;
    bool has1 = (lane < CIN - 64);            // lanes 0..31 also cover ch 64..95
    float x0 = 0.f, x1 = 0.f;
    const long hb = (long)b * NTOT * CIN;

    if (tok == 0) {                            // CLS token: no conv
        x0 = hs[hb + c0];
        if (has1) x1 = hs[hb + c1];
    } else {
        int j  = tok - 1;
        int oy = j / ow, ox = j % ow;
        #pragma unroll
        for (int dy = 0; dy < 3; ++dy) {
            int iy = oy*stride - 1 + dy;
            if (iy < 0 || iy >= HFS) continue;
            #pragma unroll
            for (int dx = 0; dx < 3; ++dx) {
                int ix = ox*stride - 1 + dx;
                if (ix < 0 || ix >= HFS) continue;
                long base = hb + (long)(1 + iy*HFS + ix) * CIN;
                x0 += hs[base + c0] * wgt[c0*9 + dy*3 + dx];
                if (has1) x1 += hs[base + c1] * wgt[c1*9 + dy*3 + dx];
            }
        }
    }

    // LayerNorm over 96 channels (wave-wide reduction)
    float s  = x0 + (has1 ? x1 : 0.f);
    float ss = x0*x0 + (has1 ? x1*x1 : 0.f);
    #pragma unroll
    for (int off = 32; off >= 1; off >>= 1) {
        s  += __shfl_xor(s,  off, 64);
        ss += __shfl_xor(ss, off, 64);
    }
    float m   = s / CIN;
    float var = ss / CIN - m*m;
    float r   = rsqrtf(var + 1e-5f);

    row_s[wid][c0] = (x0 - m)*r*g[c0] + beta[c0];
    if (has1) row_s[wid][c1] = (x1 - m)*r*g[c1] + beta[c1];
    __syncthreads();

    // Projection: out[o] = row . W[:,o] + bias[o]; lane handles o, o+64, o+128
    const float* row = row_s[wid];
    #pragma unroll
    for (int i = 0; i < 3; ++i) {
        int o = lane + i*64;
        float acc = bias[o];
        #pragma unroll 8
        for (int k = 0; k < CIN; ++k)
            acc = fmaf(row[k], W[k*192 + o], acc);
        int hh = o / 96, d = o % 96;
        outb[(((long)b*2 + hh)*ntok + tok)*96 + d] = acc;
    }
}

// ---------------------------------------------------------------------------
// Kernel 2: fused attention per (b, head, q-chunk).
// Scores = scale*q.kT + rel_h/rel_w terms, softmax(197), PV, +q residual.
// kT staged transposed (bf16) in LDS with padded cols; v read from L1/L2.
// ---------------------------------------------------------------------------
__global__ __launch_bounds__(256) void attn_kernel(
    const float* __restrict__ qp, const float* __restrict__ kp, const float* __restrict__ vp,
    const float* __restrict__ relh, const float* __restrict__ relw,
    float* __restrict__ out)
{
    __shared__ bf16  kT[96 * 198];     // [c][j], padded to 198 cols (38 KB)
    __shared__ float q_s[96];
    __shared__ float rel_s[28];        // [0:14)=eh over ky, [14:28)=ew over kx
    __shared__ float red[256];
    __shared__ float p_s[256];

    int tid   = threadIdx.x;
    int chunk = blockIdx.x % 8;
    int h     = (blockIdx.x / 8) & 1;
    int b     = blockIdx.x / 16;
    long kvbase = (long)(b*2 + h) * NK * 96;

    for (int e = tid; e < NK*96; e += 256) {
        int j = e / 96, c = e % 96;
        kT[c*198 + j] = f2b(kp[kvbase + e]);
    }
    __syncthreads();

    int q0 = chunk * 99;
    int q1 = (q0 + 99 < NQ) ? (q0 + 99) : NQ;
    const float scale = 0.10206207261596575f;   // 96^-0.5

    for (int q = q0; q < q1; ++q) {
        long qbase = ((long)(b*2 + h) * NQ + q) * 96;
        if (tid < 96) q_s[tid] = qp[qbase + tid];
        __syncthreads();

        if (q > 0 && tid < 28) {                 // rel-pos dot products
            int qy = (q-1) / QW, qx = (q-1) % QW;
            int kk = tid % 14;
            int r  = ((tid < 14) ? qy : qx) - 2*kk + 26;
            const float* R = (tid < 14) ? relh : relw;
            float acc = 0.f;
            for (int c = 0; c < 96; ++c) acc += q_s[c] * R[r*96 + c];
            rel_s[tid] = acc;
        }
        __syncthreads();

        float sv = -1e30f;
        if (tid < NK) {
            float acc = 0.f;
            #pragma unroll 8
            for (int c = 0; c < 96; ++c)
                acc = fmaf(q_s[c], b2f(kT[c*198 + tid]), acc);
            sv = acc * scale;
            if (q > 0 && tid > 0) {
                int ky = (tid-1) / 14, kx = (tid-1) % 14;
                sv += rel_s[ky] + rel_s[14 + kx];
            }
        }
        red[tid] = sv;
        __syncthreads();
        #pragma unroll
        for (int off = 128; off >= 1; off >>= 1) {
            if (tid < off) red[tid] = fmaxf(red[tid], red[tid + off]);
            __syncthreads();
        }
        float mx = red[0];
        __syncthreads();
        float p = (tid < NK) ? __expf(sv - mx) : 0.f;
        red[tid] = p;
        __syncthreads();
        #pragma unroll
        for (int off = 128; off >= 1; off >>= 1) {
            if (tid < off) red[tid] += red[tid + off];
            __syncthreads();
        }
        float inv = 1.f / red[0];
        p_s[tid] = p * inv;
        __syncthreads();

        if (tid < 96) {                          // PV + residual, write out
            float acc = 0.f;
            #pragma unroll 8
            for (int j = 0; j < NK; ++j)
                acc = fmaf(p_s[j], vp[kvbase + j*96 + tid], acc);
            if (q > 0) acc += q_s[tid];
            out[((long)(b*NQ + q))*192 + h*96 + tid] = acc;
        }
        __syncthreads();                         // protect q_s/p_s for next q
    }
}

// ---------------------------------------------------------------------------
extern "C" void kernel_launch(void* const* d_in, const int* in_sizes, int n_in,
                              void* d_out, int out_size, void* d_ws, size_t ws_size,
                              hipStream_t stream)
{
    const float* hs    = (const float*)d_in[0];
    const float* Wq    = (const float*)d_in[1];
    const float* bq    = (const float*)d_in[2];
    const float* Wk    = (const float*)d_in[3];
    const float* bk    = (const float*)d_in[4];
    const float* Wv    = (const float*)d_in[5];
    const float* bv    = (const float*)d_in[6];
    const float* pqw   = (const float*)d_in[7];
    const float* pkw   = (const float*)d_in[8];
    const float* pvw   = (const float*)d_in[9];
    const float* gq    = (const float*)d_in[10];
    const float* betaq = (const float*)d_in[11];
    const float* gk    = (const float*)d_in[12];
    const float* betak = (const float*)d_in[13];
    const float* gv    = (const float*)d_in[14];
    const float* betav = (const float*)d_in[15];
    const float* relh  = (const float*)d_in[16];
    const float* relw  = (const float*)d_in[17];
    // d_in[18], d_in[19]: height/width — fixed at 56, ignored.
    float* out = (float*)d_out;

    // workspace carve (fp32): qp 38.6 MB, kp/vp 9.7 MB each  (~58 MB total)
    float* qp = (float*)d_ws;                    // [64][2][785][96]
    float* kp = qp + (long)B_*2*NQ*96;           // [64][2][197][96]
    float* vp = kp + (long)B_*2*NK*96;           // [64][2][197][96]

    // 1: pool + LN + projection  (64*1179 tokens, 4 waves/block)
    pool_ln_proj_kernel<<<(B_*1179)/4, 256, 0, stream>>>(
        hs, pqw, pkw, pvw, gq, betaq, gk, betak, gv, betav,
        Wq, bq, Wk, bk, Wv, bv, qp, kp, vp);

    // 2: fused attention  (64 b * 2 h * 8 q-chunks)
    attn_kernel<<<B_*2*8, 256, 0, stream>>>(qp, kp, vp, relh, relw, out);
}

// Round 3
// 307.938 us; speedup vs baseline: 7.7359x; 7.7359x over previous
//
#include <hip/hip_runtime.h>
#include <hip/hip_bf16.h>

#define B_    64
#define HFS   56
#define CIN   96
#define NQ    785
#define NK    197
#define QW    28
#define KW    14
#define NTOT  3137    // 56*56+1
#define NQP   800     // q tokens padded to 16
#define NKP   208     // kv tokens padded to 16
#define NKPV  224     // PV K-dim padded to 32
#define RELR  112     // 54 rel_h rows + 54 rel_w rows + 4 pad

typedef __attribute__((ext_vector_type(8))) short short8;
typedef __attribute__((ext_vector_type(4))) float floatx4;

__device__ __forceinline__ short f2s(float x) {
    __hip_bfloat16 h = __float2bfloat16(x);
    return *reinterpret_cast<short*>(&h);
}
__device__ __forceinline__ float s2f(short s) {
    __hip_bfloat16 h; *reinterpret_cast<short*>(&h) = s;
    return __bfloat162float(h);
}
__device__ __forceinline__ short8 ld8(const short* p) {
    return *reinterpret_cast<const short8*>(p);
}

#define MFMA16(a,b,c) __builtin_amdgcn_mfma_f32_16x16x32_bf16((a),(b),(c),0,0,0)

// ---------------------------------------------------------------------------
// Kernel 0: repack W^T (bf16) and combined rel matrix (bf16).
// WT[o][c] = W[c][o];  relc rows 0..53 = rel_h, 54..107 = rel_w, 108..111 = 0.
// ---------------------------------------------------------------------------
__global__ void repack_kernel(const float* __restrict__ Wq, const float* __restrict__ Wk,
                              const float* __restrict__ Wv, const float* __restrict__ relh,
                              const float* __restrict__ relw,
                              short* __restrict__ WTq, short* __restrict__ WTk,
                              short* __restrict__ WTv, short* __restrict__ relc)
{
    int i = blockIdx.x * 256 + threadIdx.x;
    if (i < 18432)        { int o = i/96, c = i%96;            WTq[o*96+c] = f2s(Wq[c*192+o]); }
    else if (i < 36864)   { int j = i-18432; int o=j/96,c=j%96; WTk[o*96+c] = f2s(Wk[c*192+o]); }
    else if (i < 55296)   { int j = i-36864; int o=j/96,c=j%96; WTv[o*96+c] = f2s(Wv[c*192+o]); }
    else if (i < 66048) {
        int j = i - 55296;  int r = j/96, c = j%96;             // 112*96
        float v = (r < 54) ? relh[r*96+c] : ((r < 108) ? relw[(r-54)*96+c] : 0.f);
        relc[r*96+c] = f2s(v);
    }
}

// ---------------------------------------------------------------------------
// Kernel 1: depthwise 3x3 pool conv + LayerNorm -> bf16 pooled tokens.
// One wave per token; lane covers channels {lane, lane+64}. Pad rows zeroed.
// ---------------------------------------------------------------------------
__global__ __launch_bounds__(256) void pool_ln_kernel(
    const float* __restrict__ hs,
    const float* __restrict__ cwq, const float* __restrict__ cwk, const float* __restrict__ cwv,
    const float* __restrict__ gq, const float* __restrict__ betaq,
    const float* __restrict__ gk, const float* __restrict__ betak,
    const float* __restrict__ gv, const float* __restrict__ betav,
    short* __restrict__ pq, short* __restrict__ pk, short* __restrict__ pv)
{
    int wid  = threadIdx.x >> 6;
    int lane = threadIdx.x & 63;
    int gid  = blockIdx.x * 4 + wid;           // 64 * 1216 slots exactly
    int b = gid / 1216;
    int t = gid % 1216;

    const float *wgt, *g, *beta;
    short* outp;
    int tok, ow, stride, valid;
    if (t < NQP) {
        tok = t; ow = QW; stride = 2; valid = (tok < NQ);
        wgt = cwq; g = gq; beta = betaq; outp = pq + ((long)b*NQP + t)*CIN;
    } else if (t < NQP + NKP) {
        tok = t - NQP; ow = KW; stride = 4; valid = (tok < NK);
        wgt = cwk; g = gk; beta = betak; outp = pk + ((long)b*NKP + tok)*CIN;
    } else {
        tok = t - NQP - NKP; ow = KW; stride = 4; valid = (tok < NK);
        wgt = cwv; g = gv; beta = betav; outp = pv + ((long)b*NKP + tok)*CIN;
    }

    int c0 = lane, c1 = lane + 64;
    bool has1 = (lane < CIN - 64);
    if (!valid) {                               // zero padded rows (wave-uniform)
        outp[c0] = 0; if (has1) outp[c1] = 0;
        return;
    }

    float x0 = 0.f, x1 = 0.f;
    const long hb = (long)b * NTOT * CIN;
    if (tok == 0) {
        x0 = hs[hb + c0];
        if (has1) x1 = hs[hb + c1];
    } else {
        int j  = tok - 1;
        int oy = j / ow, ox = j % ow;
        #pragma unroll
        for (int dy = 0; dy < 3; ++dy) {
            int iy = oy*stride - 1 + dy;
            if (iy < 0 || iy >= HFS) continue;
            #pragma unroll
            for (int dx = 0; dx < 3; ++dx) {
                int ix = ox*stride - 1 + dx;
                if (ix < 0 || ix >= HFS) continue;
                long base = hb + (long)(1 + iy*HFS + ix) * CIN;
                x0 += hs[base + c0] * wgt[c0*9 + dy*3 + dx];
                if (has1) x1 += hs[base + c1] * wgt[c1*9 + dy*3 + dx];
            }
        }
    }

    float s  = x0 + (has1 ? x1 : 0.f);
    float ss = x0*x0 + (has1 ? x1*x1 : 0.f);
    #pragma unroll
    for (int off = 32; off >= 1; off >>= 1) {
        s  += __shfl_xor(s,  off, 64);
        ss += __shfl_xor(ss, off, 64);
    }
    float m   = s / CIN;
    float var = ss / CIN - m*m;
    float r   = rsqrtf(var + 1e-5f);
    outp[c0] = f2s((x0 - m)*r*g[c0] + beta[c0]);
    if (has1) outp[c1] = f2s((x1 - m)*r*g[c1] + beta[c1]);
}

// ---------------------------------------------------------------------------
// Kernel 2: projections as MFMA GEMM. One wave per 16-token tile.
// q -> qb bf16 [bh][800][96]; k -> kb bf16 [bh][208][96]; v -> vt bf16 [bh][96][224].
// ---------------------------------------------------------------------------
__global__ __launch_bounds__(256) void proj_mfma_kernel(
    const short* __restrict__ pq, const short* __restrict__ pk, const short* __restrict__ pv,
    const short* __restrict__ WTq, const short* __restrict__ WTk, const short* __restrict__ WTv,
    const float* __restrict__ bq, const float* __restrict__ bk, const float* __restrict__ bv,
    short* __restrict__ qb, short* __restrict__ kb, short* __restrict__ vt)
{
    int wid  = threadIdx.x >> 6;
    int lane = threadIdx.x & 63;
    int quad = lane >> 4, col = lane & 15;
    int wt = blockIdx.x * 4 + wid;              // 4864 tiles total

    const short *A, *WT; const float* bias;
    int mode, ntokp, row0;
    if (wt < 3200)      { A = pq; WT = WTq; bias = bq; mode = 0; ntokp = NQP; row0 = wt*16; }
    else if (wt < 4032) { A = pk; WT = WTk; bias = bk; mode = 1; ntokp = NKP; row0 = (wt-3200)*16; }
    else                { A = pv; WT = WTv; bias = bv; mode = 2; ntokp = NKP; row0 = (wt-4032)*16; }

    short8 a[3];
    #pragma unroll
    for (int c = 0; c < 3; ++c)
        a[c] = ld8(A + (long)(row0 + col)*96 + c*32 + quad*8);

    int b = row0 / ntokp;
    int tloc0 = row0 % ntokp;

    #pragma unroll
    for (int nt = 0; nt < 12; ++nt) {
        floatx4 acc = {0.f, 0.f, 0.f, 0.f};
        #pragma unroll
        for (int c = 0; c < 3; ++c) {
            short8 bf = ld8(WT + (nt*16 + col)*96 + c*32 + quad*8);
            acc = MFMA16(a[c], bf, acc);
        }
        int o = nt*16 + col;
        int h = (o >= 96) ? 1 : 0;
        int d = o - h*96;
        float bo = bias[o];
        #pragma unroll
        for (int reg = 0; reg < 4; ++reg) {
            int tok = tloc0 + quad*4 + reg;
            short val = f2s(acc[reg] + bo);
            if (mode == 2)
                vt[((long)(b*2 + h)*96 + d)*NKPV + tok] = val;
            else if (mode == 0)
                qb[((long)(b*2 + h)*NQP + tok)*96 + d] = val;
            else
                kb[((long)(b*2 + h)*NKP + tok)*96 + d] = val;
        }
    }
}

// ---------------------------------------------------------------------------
// Kernel 3: MFMA attention. One wave per 16-q-row tile (no cross-wave sync).
// S = QK^T (13x3 MFMA) + rel via E = Q Rel^T (7x3 MFMA, LDS gather),
// in-register softmax (16-lane shuffles), P -> LDS A-layout, PV (7x6 MFMA),
// epilogue: *1/sum + q residual.
// ---------------------------------------------------------------------------
__global__ __launch_bounds__(256) void attn_kernel(
    const short* __restrict__ qb, const short* __restrict__ kb,
    const short* __restrict__ vt, const short* __restrict__ relc,
    float* __restrict__ out)
{
    __shared__ __align__(16) float e_s[4][16][RELR];     // 28 KB
    __shared__ __align__(16) short p_s[4][16][NKPV + 8]; // 29 KB (+8 pad: 2-way banks)

    int wid  = threadIdx.x >> 6;
    int lane = threadIdx.x & 63;
    int quad = lane >> 4, col = lane & 15;
    int wt = blockIdx.x * 4 + wid;              // 6400 tiles
    int bh = wt / 50;
    int t  = wt % 50;
    int q0 = t * 16;

    // Q A-fragments
    const short* qrow = qb + ((long)bh*NQP + q0)*96;
    short8 aq[3];
    #pragma unroll
    for (int c = 0; c < 3; ++c)
        aq[c] = ld8(qrow + col*96 + c*32 + quad*8);

    // S = Q K^T  (13 col-tiles cover k = 0..207)
    floatx4 s[13];
    const short* kbase = kb + (long)bh*NKP*96;
    #pragma unroll
    for (int kt = 0; kt < 13; ++kt) {
        floatx4 acc = {0.f, 0.f, 0.f, 0.f};
        #pragma unroll
        for (int c = 0; c < 3; ++c) {
            short8 bf = ld8(kbase + (kt*16 + col)*96 + c*32 + quad*8);
            acc = MFMA16(aq[c], bf, acc);
        }
        s[kt] = acc;
    }

    // E = Q Rel^T  (rows 0..53 = rel_h dots, 54..107 = rel_w dots)
    #pragma unroll
    for (int rt = 0; rt < 7; ++rt) {
        floatx4 acc = {0.f, 0.f, 0.f, 0.f};
        #pragma unroll
        for (int c = 0; c < 3; ++c) {
            short8 bf = ld8(relc + (rt*16 + col)*96 + c*32 + quad*8);
            acc = MFMA16(aq[c], bf, acc);
        }
        #pragma unroll
        for (int reg = 0; reg < 4; ++reg)
            e_s[wid][quad*4 + reg][rt*16 + col] = acc[reg];
    }

    // softmax per row (rows live in 16-lane quad groups)
    const float scale = 0.10206207261596575f;   // 96^-0.5
    float inv[4];
    #pragma unroll
    for (int reg = 0; reg < 4; ++reg) {
        int row = quad*4 + reg;
        int q   = q0 + row;
        int qy = 0, qx = 0;
        if (q > 0) { qy = (q-1) / QW; qx = (q-1) % QW; }
        float mx = -1e30f;
        #pragma unroll
        for (int kt = 0; kt < 13; ++kt) {
            int k = kt*16 + col;
            float v = s[kt][reg] * scale;
            if (q > 0 && k > 0 && k < NK) {
                int ky = (k-1) / KW, kx = (k-1) % KW;
                v += e_s[wid][row][qy - 2*ky + 26] + e_s[wid][row][54 + qx - 2*kx + 26];
            }
            if (k >= NK) v = -1e30f;
            s[kt][reg] = v;
            mx = fmaxf(mx, v);
        }
        mx = fmaxf(mx, __shfl_xor(mx, 1));
        mx = fmaxf(mx, __shfl_xor(mx, 2));
        mx = fmaxf(mx, __shfl_xor(mx, 4));
        mx = fmaxf(mx, __shfl_xor(mx, 8));
        float sum = 0.f;
        #pragma unroll
        for (int kt = 0; kt < 13; ++kt) {
            float p = __expf(s[kt][reg] - mx);
            sum += p;
            p_s[wid][row][kt*16 + col] = f2s(p);
        }
        sum += __shfl_xor(sum, 1);
        sum += __shfl_xor(sum, 2);
        sum += __shfl_xor(sum, 4);
        sum += __shfl_xor(sum, 8);
        inv[reg] = 1.f / sum;
        p_s[wid][row][208 + col] = 0;           // zero PV pad cols 208..223
    }

    // O = P V   (K-dim 224 = 7 chunks of 32; out channels 96 = 6 n-tiles)
    floatx4 o[6];
    #pragma unroll
    for (int nt = 0; nt < 6; ++nt) o[nt] = floatx4{0.f, 0.f, 0.f, 0.f};
    const short* vbase = vt + (long)bh*96*NKPV;
    #pragma unroll
    for (int c = 0; c < 7; ++c) {
        short8 ap = ld8(&p_s[wid][col][c*32 + quad*8]);
        #pragma unroll
        for (int nt = 0; nt < 6; ++nt) {
            short8 bf = ld8(vbase + (nt*16 + col)*NKPV + c*32 + quad*8);
            o[nt] = MFMA16(ap, bf, o[nt]);
        }
    }

    // epilogue: normalize, + residual q, store
    int b = bh >> 1, h = bh & 1;
    #pragma unroll
    for (int nt = 0; nt < 6; ++nt) {
        int ch = nt*16 + col;
        #pragma unroll
        for (int reg = 0; reg < 4; ++reg) {
            int q = q0 + quad*4 + reg;
            if (q < NQ) {
                float val = o[nt][reg] * inv[reg];
                if (q > 0) val += s2f(qb[((long)bh*NQP + q)*96 + ch]);
                out[((long)b*NQ + q)*192 + h*96 + ch] = val;
            }
        }
    }
}

// ---------------------------------------------------------------------------
extern "C" void kernel_launch(void* const* d_in, const int* in_sizes, int n_in,
                              void* d_out, int out_size, void* d_ws, size_t ws_size,
                              hipStream_t stream)
{
    const float* hs    = (const float*)d_in[0];
    const float* Wq    = (const float*)d_in[1];
    const float* bq    = (const float*)d_in[2];
    const float* Wk    = (const float*)d_in[3];
    const float* bk    = (const float*)d_in[4];
    const float* Wv    = (const float*)d_in[5];
    const float* bv    = (const float*)d_in[6];
    const float* pqw   = (const float*)d_in[7];
    const float* pkw   = (const float*)d_in[8];
    const float* pvw   = (const float*)d_in[9];
    const float* gq    = (const float*)d_in[10];
    const float* betaq = (const float*)d_in[11];
    const float* gk    = (const float*)d_in[12];
    const float* betak = (const float*)d_in[13];
    const float* gv    = (const float*)d_in[14];
    const float* betav = (const float*)d_in[15];
    const float* relh  = (const float*)d_in[16];
    const float* relw  = (const float*)d_in[17];
    float* out = (float*)d_out;

    // workspace carve (bf16 stored as short) — ~45 MB total
    short* pq   = (short*)d_ws;                  // [64][800][96]
    short* pk   = pq  + (long)B_*NQP*CIN;        // [64][208][96]
    short* pv   = pk  + (long)B_*NKP*CIN;        // [64][208][96]
    short* qb   = pv  + (long)B_*NKP*CIN;        // [128][800][96]
    short* kb   = qb  + (long)128*NQP*96;        // [128][208][96]
    short* vt   = kb  + (long)128*NKP*96;        // [128][96][224]
    short* WTq  = vt  + (long)128*96*NKPV;       // [192][96]
    short* WTk  = WTq + 192*96;
    short* WTv  = WTk + 192*96;
    short* relc = WTv + 192*96;                  // [112][96]

    repack_kernel<<<258, 256, 0, stream>>>(Wq, Wk, Wv, relh, relw, WTq, WTk, WTv, relc);

    pool_ln_kernel<<<(B_*1216)/4, 256, 0, stream>>>(
        hs, pqw, pkw, pvw, gq, betaq, gk, betak, gv, betav, pq, pk, pv);

    proj_mfma_kernel<<<4864/4, 256, 0, stream>>>(
        pq, pk, pv, WTq, WTk, WTv, bq, bk, bv, qb, kb, vt);

    attn_kernel<<<6400/4, 256, 0, stream>>>(qb, kb, vt, relc, out);
}

// Round 4
// 288.513 us; speedup vs baseline: 8.2567x; 1.0673x over previous
//
#include <hip/hip_runtime.h>
#include <hip/hip_bf16.h>

#define B_    64
#define HFS   56
#define CIN   96
#define NQ    785
#define NK    197
#define QW    28
#define KW    14
#define NTOT  3137    // 56*56+1
#define NQP   800     // q tokens padded to 16
#define NKP   208     // kv tokens padded to 16
#define NKPV  224     // PV K-dim padded to 32
#define VROWS 112     // 96 v channels + ones row + 15 zero rows
#define KSCL  0.10206207261596575f   // 96^-0.5, folded into Wk

typedef __attribute__((ext_vector_type(8))) short short8;
typedef __attribute__((ext_vector_type(4))) float floatx4;

__device__ __forceinline__ short f2s(float x) {
    __hip_bfloat16 h = __float2bfloat16(x);
    return *reinterpret_cast<short*>(&h);
}
__device__ __forceinline__ float s2f(short s) {
    __hip_bfloat16 h; *reinterpret_cast<short*>(&h) = s;
    return __bfloat162float(h);
}
__device__ __forceinline__ short8 ld8(const short* p) {
    return *reinterpret_cast<const short8*>(p);
}

#define MFMA16(a,b,c) __builtin_amdgcn_mfma_f32_16x16x32_bf16((a),(b),(c),0,0,0)

// ---------------------------------------------------------------------------
// Kernel 0: prep = repack W^T (bf16; Wk pre-scaled by 96^-0.5), rel matrix,
// and init vt rows 96..111 (ones row / zeros) + zero pad-cols 208..223.
// ---------------------------------------------------------------------------
__global__ void prep_kernel(const float* __restrict__ Wq, const float* __restrict__ Wk,
                            const float* __restrict__ Wv, const float* __restrict__ relh,
                            const float* __restrict__ relw,
                            short* __restrict__ WTq, short* __restrict__ WTk,
                            short* __restrict__ WTv, short* __restrict__ relc,
                            short* __restrict__ vt)
{
    int i = blockIdx.x * 256 + threadIdx.x;           // 721408 total
    if (i < 18432)      { int o = i/96, c = i%96;              WTq[o*96+c] = f2s(Wq[c*192+o]); }
    else if (i < 36864) { int j = i-18432; int o=j/96,c=j%96;  WTk[o*96+c] = f2s(Wk[c*192+o]*KSCL); }
    else if (i < 55296) { int j = i-36864; int o=j/96,c=j%96;  WTv[o*96+c] = f2s(Wv[c*192+o]); }
    else if (i < 66048) {
        int j = i - 55296;  int r = j/96, c = j%96;            // 112*96
        float v = (r < 54) ? relh[r*96+c] : ((r < 108) ? relw[(r-54)*96+c] : 0.f);
        relc[r*96+c] = f2s(v);
    } else {
        int j2 = i - 66048;                                     // 128 * 5120
        int bh = j2 / 5120, r = j2 % 5120;
        int row, tok; short val;
        if (r < 3584) { row = 96 + r/224; tok = r%224;
                        val = (row == 96 && tok < NK) ? (short)0x3F80 : (short)0; }
        else          { int rr = r-3584; row = rr/16; tok = 208 + (rr%16); val = 0; }
        vt[((long)bh*VROWS + row)*NKPV + tok] = val;
    }
}

// ---------------------------------------------------------------------------
// Kernel 1: depthwise 3x3 pool conv + LayerNorm -> bf16 pooled tokens.
// One wave per token; lane covers channels {lane, lane+64}.
// k and v convs fused in one wave (shared hs reads). Pad rows zeroed.
// ---------------------------------------------------------------------------
__device__ __forceinline__ void ln_store(float x0, float x1, bool has1,
    const float* __restrict__ g, const float* __restrict__ beta,
    short* __restrict__ outp, int c0, int c1)
{
    float s  = x0 + (has1 ? x1 : 0.f);
    float ss = x0*x0 + (has1 ? x1*x1 : 0.f);
    #pragma unroll
    for (int off = 32; off >= 1; off >>= 1) {
        s  += __shfl_xor(s,  off, 64);
        ss += __shfl_xor(ss, off, 64);
    }
    float m   = s / CIN;
    float var = ss / CIN - m*m;
    float r   = rsqrtf(var + 1e-5f);
    outp[c0] = f2s((x0 - m)*r*g[c0] + beta[c0]);
    if (has1) outp[c1] = f2s((x1 - m)*r*g[c1] + beta[c1]);
}

__global__ __launch_bounds__(256) void pool_ln_kernel(
    const float* __restrict__ hs,
    const float* __restrict__ cwq, const float* __restrict__ cwk, const float* __restrict__ cwv,
    const float* __restrict__ gq, const float* __restrict__ betaq,
    const float* __restrict__ gk, const float* __restrict__ betak,
    const float* __restrict__ gv, const float* __restrict__ betav,
    short* __restrict__ pq, short* __restrict__ pk, short* __restrict__ pv)
{
    int wid  = threadIdx.x >> 6;
    int lane = threadIdx.x & 63;
    int gid  = blockIdx.x * 4 + wid;           // 64 * 1008 slots exactly
    int b = gid / 1008;
    int t = gid % 1008;
    int c0 = lane, c1 = lane + 64;
    bool has1 = (lane < 32);
    const long hb = (long)b * NTOT * CIN;

    if (t < NQP) {                              // ---- q path (stride 2) ----
        short* outp = pq + ((long)b*NQP + t)*CIN;
        if (t >= NQ) { outp[c0] = 0; if (has1) outp[c1] = 0; return; }
        float x0 = 0.f, x1 = 0.f;
        if (t == 0) {
            x0 = hs[hb + c0];
            if (has1) x1 = hs[hb + c1];
        } else {
            int j = t - 1, oy = j / QW, ox = j % QW;
            #pragma unroll
            for (int dy = 0; dy < 3; ++dy) {
                int iy = oy*2 - 1 + dy;
                if (iy < 0 || iy >= HFS) continue;
                #pragma unroll
                for (int dx = 0; dx < 3; ++dx) {
                    int ix = ox*2 - 1 + dx;
                    if (ix < 0 || ix >= HFS) continue;
                    long base = hb + (long)(1 + iy*HFS + ix) * CIN;
                    x0 += hs[base + c0] * cwq[c0*9 + dy*3 + dx];
                    if (has1) x1 += hs[base + c1] * cwq[c1*9 + dy*3 + dx];
                }
            }
        }
        ln_store(x0, x1, has1, gq, betaq, outp, c0, c1);
    } else {                                    // ---- k+v fused (stride 4) ----
        int tok = t - NQP;
        short* ok_ = pk + ((long)b*NKP + tok)*CIN;
        short* ov_ = pv + ((long)b*NKP + tok)*CIN;
        if (tok >= NK) {
            ok_[c0] = 0; ov_[c0] = 0;
            if (has1) { ok_[c1] = 0; ov_[c1] = 0; }
            return;
        }
        float k0 = 0.f, k1 = 0.f, v0 = 0.f, v1 = 0.f;
        if (tok == 0) {
            float x0 = hs[hb + c0]; k0 = v0 = x0;
            if (has1) { float x1 = hs[hb + c1]; k1 = v1 = x1; }
        } else {
            int j = tok - 1, oy = j / KW, ox = j % KW;
            #pragma unroll
            for (int dy = 0; dy < 3; ++dy) {
                int iy = oy*4 - 1 + dy;
                if (iy < 0 || iy >= HFS) continue;
                #pragma unroll
                for (int dx = 0; dx < 3; ++dx) {
                    int ix = ox*4 - 1 + dx;
                    if (ix < 0 || ix >= HFS) continue;
                    long base = hb + (long)(1 + iy*HFS + ix) * CIN;
                    int wi0 = c0*9 + dy*3 + dx, wi1 = c1*9 + dy*3 + dx;
                    float x0 = hs[base + c0];
                    k0 += x0 * cwk[wi0];  v0 += x0 * cwv[wi0];
                    if (has1) {
                        float x1 = hs[base + c1];
                        k1 += x1 * cwk[wi1];  v1 += x1 * cwv[wi1];
                    }
                }
            }
        }
        ln_store(k0, k1, has1, gk, betak, ok_, c0, c1);
        ln_store(v0, v1, has1, gv, betav, ov_, c0, c1);
    }
}

// ---------------------------------------------------------------------------
// Kernel 2: projections as MFMA GEMM. One wave per 16-token tile.
// q -> qb [bh][800][96]; k -> kb [bh][208][96] (scale folded in WTk);
// v -> vt [bh][112][224] transposed, padded tokens zeroed.
// ---------------------------------------------------------------------------
__global__ __launch_bounds__(256) void proj_mfma_kernel(
    const short* __restrict__ pq, const short* __restrict__ pk, const short* __restrict__ pv,
    const short* __restrict__ WTq, const short* __restrict__ WTk, const short* __restrict__ WTv,
    const float* __restrict__ bq, const float* __restrict__ bk, const float* __restrict__ bv,
    short* __restrict__ qb, short* __restrict__ kb, short* __restrict__ vt)
{
    int wid  = threadIdx.x >> 6;
    int lane = threadIdx.x & 63;
    int quad = lane >> 4, col = lane & 15;
    int wt = blockIdx.x * 4 + wid;              // 4864 tiles total

    const short *A, *WT; const float* bias;
    int mode, ntokp, row0;
    float bsc;
    if (wt < 3200)      { A = pq; WT = WTq; bias = bq; mode = 0; ntokp = NQP; row0 = wt*16; bsc = 1.f; }
    else if (wt < 4032) { A = pk; WT = WTk; bias = bk; mode = 1; ntokp = NKP; row0 = (wt-3200)*16; bsc = KSCL; }
    else                { A = pv; WT = WTv; bias = bv; mode = 2; ntokp = NKP; row0 = (wt-4032)*16; bsc = 1.f; }

    short8 a[3];
    #pragma unroll
    for (int c = 0; c < 3; ++c)
        a[c] = ld8(A + (long)(row0 + col)*96 + c*32 + quad*8);

    int b = row0 / ntokp;
    int tloc0 = row0 % ntokp;

    #pragma unroll
    for (int nt = 0; nt < 12; ++nt) {
        floatx4 acc = {0.f, 0.f, 0.f, 0.f};
        #pragma unroll
        for (int c = 0; c < 3; ++c) {
            short8 bf = ld8(WT + (nt*16 + col)*96 + c*32 + quad*8);
            acc = MFMA16(a[c], bf, acc);
        }
        int o = nt*16 + col;
        int h = (o >= 96) ? 1 : 0;
        int d = o - h*96;
        float bo = bias[o] * bsc;
        #pragma unroll
        for (int reg = 0; reg < 4; ++reg) {
            int tok = tloc0 + quad*4 + reg;
            float fv = acc[reg] + bo;
            if (mode == 2) {
                short val = (tok < NK) ? f2s(fv) : (short)0;
                vt[((long)(b*2 + h)*VROWS + d)*NKPV + tok] = val;
            } else if (mode == 0) {
                qb[((long)(b*2 + h)*NQP + tok)*96 + d] = f2s(fv);
            } else {
                kb[((long)(b*2 + h)*NKP + tok)*96 + d] = f2s(fv);
            }
        }
    }
}

// ---------------------------------------------------------------------------
// Kernel 3: MFMA attention, one wave per 16-q-row tile.
// E = Q Rel^T -> LDS (bf16). Fused S-MFMA + bias-gather + exp per k-tile
// (no max-sub: |s| < 1). Row sums via ones-row appended to V^T (7th n-tile).
// Epilogue: broadcast sum, *1/sum, +q residual. XCD-swizzled block order.
// ---------------------------------------------------------------------------
__global__ __launch_bounds__(256) void attn_kernel(
    const short* __restrict__ qb, const short* __restrict__ kb,
    const short* __restrict__ vt, const short* __restrict__ relc,
    float* __restrict__ out)
{
    __shared__ short e_s[4][16][112];                 // bf16 E (14 KB)
    __shared__ __align__(16) short p_s[4][16][232];   // bf16 P (29 KB)

    int tid  = threadIdx.x;
    int wid  = tid >> 6;
    int lane = tid & 63;
    int quad = lane >> 4, col = lane & 15;

    int bid = blockIdx.x;                      // 1600 = 8 * 200
    int tb  = (bid & 7) * 200 + (bid >> 3);    // XCD-contiguous tile ranges
    int wt  = tb * 4 + wid;
    int bh  = wt / 50;
    int t   = wt % 50;
    int q0  = t * 16;

    // Q A-fragments
    const short* qrow = qb + ((long)bh*NQP + q0)*96;
    short8 aq[3];
    #pragma unroll
    for (int c = 0; c < 3; ++c)
        aq[c] = ld8(qrow + col*96 + c*32 + quad*8);

    // E = Q Rel^T  (cols 0..53 = rel_h dots, 54..107 = rel_w dots)
    #pragma unroll
    for (int rt = 0; rt < 7; ++rt) {
        floatx4 acc = {0.f, 0.f, 0.f, 0.f};
        #pragma unroll
        for (int c = 0; c < 3; ++c) {
            short8 bf = ld8(relc + (rt*16 + col)*96 + c*32 + quad*8);
            acc = MFMA16(aq[c], bf, acc);
        }
        #pragma unroll
        for (int reg = 0; reg < 4; ++reg)
            e_s[wid][quad*4 + reg][rt*16 + col] = f2s(acc[reg]);
    }
    // (within-wave LDS ops are in-order; no barrier needed — e_s/p_s are per-wave)

    // per-row q spatial coords
    int qyo[4], qxo[4];
    #pragma unroll
    for (int reg = 0; reg < 4; ++reg) {
        int qq = q0 + quad*4 + reg;
        int jj = (qq > 0) ? (qq - 1) : 0;
        qyo[reg] = jj / QW;
        qxo[reg] = jj % QW;
    }

    // fused S = Q K^T (scale pre-folded) + rel bias + exp -> P (bf16 LDS)
    const short* kbase = kb + (long)bh*NKP*96;
    #pragma unroll
    for (int kt = 0; kt < 13; ++kt) {
        floatx4 acc = {0.f, 0.f, 0.f, 0.f};
        #pragma unroll
        for (int c = 0; c < 3; ++c) {
            short8 bf = ld8(kbase + (kt*16 + col)*96 + c*32 + quad*8);
            acc = MFMA16(aq[c], bf, acc);
        }
        int k  = kt*16 + col;
        int kk = (k > 0) ? (k - 1) : 0;
        int ky = kk / 14;  ky = (ky < 13) ? ky : 13;
        int kx = kk - 14*ky;
        int oh = 26 - 2*ky;
        int ow2 = 26 - 2*kx;
        #pragma unroll
        for (int reg = 0; reg < 4; ++reg) {
            const short* er = &e_s[wid][quad*4 + reg][0];
            float bias = s2f(er[qyo[reg] + oh]) + s2f(er[54 + qxo[reg] + ow2]);
            if (kt == 0) bias = (col == 0) ? 0.f : bias;              // CLS col
            if (q0 == 0 && reg == 0) bias = (quad == 0) ? 0.f : bias; // CLS row
            p_s[wid][quad*4 + reg][k] = f2s(__expf(acc[reg] + bias));
        }
    }
    #pragma unroll
    for (int reg = 0; reg < 4; ++reg)          // zero PV pad cols 208..223
        p_s[wid][quad*4 + reg][208 + col] = 0;

    // O = P V  (7 K-chunks of 32; 6 V n-tiles + 1 ones-row n-tile = row sums)
    floatx4 o[7];
    #pragma unroll
    for (int nt = 0; nt < 7; ++nt) o[nt] = floatx4{0.f, 0.f, 0.f, 0.f};
    const short* vbase = vt + (long)bh*VROWS*NKPV;
    #pragma unroll
    for (int c = 0; c < 7; ++c) {
        short8 ap = ld8(&p_s[wid][col][c*32 + quad*8]);
        #pragma unroll
        for (int nt = 0; nt < 7; ++nt) {
            short8 bf = ld8(vbase + (nt*16 + col)*NKPV + c*32 + quad*8);
            o[nt] = MFMA16(ap, bf, o[nt]);
        }
    }

    // epilogue: broadcast row sum (col 0 of n-tile 6), normalize, +residual
    float inv[4];
    #pragma unroll
    for (int reg = 0; reg < 4; ++reg) {
        float srow = __shfl(o[6][reg], lane & 48, 64);
        inv[reg] = 1.0f / srow;
    }
    int b = bh >> 1, h = bh & 1;
    #pragma unroll
    for (int nt = 0; nt < 6; ++nt) {
        int ch = nt*16 + col;
        #pragma unroll
        for (int reg = 0; reg < 4; ++reg) {
            int q = q0 + quad*4 + reg;
            if (q < NQ) {
                float val = o[nt][reg] * inv[reg];
                if (q > 0) val += s2f(qb[((long)bh*NQP + q)*96 + ch]);
                out[((long)b*NQ + q)*192 + h*96 + ch] = val;
            }
        }
    }
}

// ---------------------------------------------------------------------------
extern "C" void kernel_launch(void* const* d_in, const int* in_sizes, int n_in,
                              void* d_out, int out_size, void* d_ws, size_t ws_size,
                              hipStream_t stream)
{
    const float* hs    = (const float*)d_in[0];
    const float* Wq    = (const float*)d_in[1];
    const float* bq    = (const float*)d_in[2];
    const float* Wk    = (const float*)d_in[3];
    const float* bk    = (const float*)d_in[4];
    const float* Wv    = (const float*)d_in[5];
    const float* bv    = (const float*)d_in[6];
    const float* pqw   = (const float*)d_in[7];
    const float* pkw   = (const float*)d_in[8];
    const float* pvw   = (const float*)d_in[9];
    const float* gq    = (const float*)d_in[10];
    const float* betaq = (const float*)d_in[11];
    const float* gk    = (const float*)d_in[12];
    const float* betak = (const float*)d_in[13];
    const float* gv    = (const float*)d_in[14];
    const float* betav = (const float*)d_in[15];
    const float* relh  = (const float*)d_in[16];
    const float* relw  = (const float*)d_in[17];
    float* out = (float*)d_out;

    // workspace carve (bf16 as short) — ~46.3 MB
    short* pq   = (short*)d_ws;                  // [64][800][96]
    short* pk   = pq  + (long)B_*NQP*CIN;        // [64][208][96]
    short* pv   = pk  + (long)B_*NKP*CIN;        // [64][208][96]
    short* qb   = pv  + (long)B_*NKP*CIN;        // [128][800][96]
    short* kb   = qb  + (long)128*NQP*96;        // [128][208][96]
    short* vt   = kb  + (long)128*NKP*96;        // [128][112][224]
    short* WTq  = vt  + (long)128*VROWS*NKPV;    // [192][96]
    short* WTk  = WTq + 192*96;
    short* WTv  = WTk + 192*96;
    short* relc = WTv + 192*96;                  // [112][96]

    prep_kernel<<<2818, 256, 0, stream>>>(Wq, Wk, Wv, relh, relw,
                                          WTq, WTk, WTv, relc, vt);

    pool_ln_kernel<<<(B_*1008)/4, 256, 0, stream>>>(
        hs, pqw, pkw, pvw, gq, betaq, gk, betak, gv, betav, pq, pk, pv);

    proj_mfma_kernel<<<4864/4, 256, 0, stream>>>(
        pq, pk, pv, WTq, WTk, WTv, bq, bk, bv, qb, kb, vt);

    attn_kernel<<<1600, 256, 0, stream>>>(qb, kb, vt, relc, out);
}

// Round 6
// 276.460 us; speedup vs baseline: 8.6167x; 1.0436x over previous
//
#include <hip/hip_runtime.h>
#include <hip/hip_bf16.h>

#define B_    64
#define HFS   56
#define CIN   96
#define NQ    785
#define NK    197
#define QW    28
#define KW    14
#define NTOT  3137    // 56*56+1
#define NQP   800     // q tokens padded to 16
#define NKP   208     // kv tokens padded to 16
#define NKPV  224     // PV K-dim padded to 32
#define VROWS 112     // 96 v channels + ones row + 15 zero rows
#define KSCL  0.10206207261596575f   // 96^-0.5, folded into Wk

typedef __attribute__((ext_vector_type(8))) short short8;
typedef __attribute__((ext_vector_type(4))) short shortx4;
typedef __attribute__((ext_vector_type(4))) float floatx4;

__device__ __forceinline__ short f2s(float x) {
    __hip_bfloat16 h = __float2bfloat16(x);
    return *reinterpret_cast<short*>(&h);
}
__device__ __forceinline__ float s2f(short s) {
    __hip_bfloat16 h; *reinterpret_cast<short*>(&h) = s;
    return __bfloat162float(h);
}
__device__ __forceinline__ short8 ld8(const short* p) {
    return *reinterpret_cast<const short8*>(p);
}

#define MFMA16(a,b,c) __builtin_amdgcn_mfma_f32_16x16x32_bf16((a),(b),(c),0,0,0)

// ---------------------------------------------------------------------------
// Kernel 0: prep = repack W^T (bf16; Wk pre-scaled), rel matrix, vt pad init,
// and conv-weight transposes cwT[9][96] (fp32, coalesced reads in pool).
// ---------------------------------------------------------------------------
__global__ void prep_kernel(const float* __restrict__ Wq, const float* __restrict__ Wk,
                            const float* __restrict__ Wv, const float* __restrict__ relh,
                            const float* __restrict__ relw,
                            const float* __restrict__ pqw, const float* __restrict__ pkw,
                            const float* __restrict__ pvw,
                            short* __restrict__ WTq, short* __restrict__ WTk,
                            short* __restrict__ WTv, short* __restrict__ relc,
                            short* __restrict__ vt,
                            float* __restrict__ cwqT, float* __restrict__ cwkT,
                            float* __restrict__ cwvT)
{
    int i = blockIdx.x * 256 + threadIdx.x;           // 724000 total
    if (i < 18432)      { int o = i/96, c = i%96;              WTq[o*96+c] = f2s(Wq[c*192+o]); }
    else if (i < 36864) { int j = i-18432; int o=j/96,c=j%96;  WTk[o*96+c] = f2s(Wk[c*192+o]*KSCL); }
    else if (i < 55296) { int j = i-36864; int o=j/96,c=j%96;  WTv[o*96+c] = f2s(Wv[c*192+o]); }
    else if (i < 66048) {
        int j = i - 55296;  int r = j/96, c = j%96;            // 112*96
        float v = (r < 54) ? relh[r*96+c] : ((r < 108) ? relw[(r-54)*96+c] : 0.f);
        relc[r*96+c] = f2s(v);
    } else if (i < 721408) {
        int j2 = i - 66048;                                     // 128 * 5120
        int bh = j2 / 5120, r = j2 % 5120;
        int row, tok; short val;
        if (r < 3584) { row = 96 + r/224; tok = r%224;
                        val = (row == 96 && tok < NK) ? (short)0x3F80 : (short)0; }
        else          { int rr = r-3584; row = rr/16; tok = 208 + (rr%16); val = 0; }
        vt[((long)bh*VROWS + row)*NKPV + tok] = val;
    } else if (i < 724000) {
        int j = i - 721408;                                     // 3 * 864
        int w = j / 864, r = j % 864;
        int c = r / 9, off = r % 9;
        const float* src = (w == 0) ? pqw : (w == 1) ? pkw : pvw;
        float*       dst = (w == 0) ? cwqT : (w == 1) ? cwkT : cwvT;
        dst[off*96 + c] = src[c*9 + off];
    }
}

// ---------------------------------------------------------------------------
// Kernel 1: depthwise 3x3 pool conv + LayerNorm -> bf16 pooled tokens.
// One wave per token; lanes 0..47 each handle 2 channels (float2 loads).
// k and v convs fused in one wave (shared hs reads). Pad rows zeroed.
// ---------------------------------------------------------------------------
__device__ __forceinline__ void ln_store2(float xa, float xb, bool act,
    const float* __restrict__ g, const float* __restrict__ beta,
    short* __restrict__ outp, int c)
{
    float s  = act ? (xa + xb) : 0.f;
    float ss = act ? (xa*xa + xb*xb) : 0.f;
    #pragma unroll
    for (int off = 32; off >= 1; off >>= 1) {
        s  += __shfl_xor(s,  off, 64);
        ss += __shfl_xor(ss, off, 64);
    }
    float m   = s / CIN;
    float var = ss / CIN - m*m;
    float r   = rsqrtf(var + 1e-5f);
    if (act) {
        float2 g2 = *reinterpret_cast<const float2*>(g + c);
        float2 b2 = *reinterpret_cast<const float2*>(beta + c);
        unsigned pa = (unsigned short)f2s((xa - m)*r*g2.x + b2.x);
        unsigned pb = (unsigned short)f2s((xb - m)*r*g2.y + b2.y);
        *reinterpret_cast<unsigned*>(outp + c) = pa | (pb << 16);
    }
}

__global__ __launch_bounds__(256) void pool_ln_kernel(
    const float* __restrict__ hs,
    const float* __restrict__ cwqT, const float* __restrict__ cwkT, const float* __restrict__ cwvT,
    const float* __restrict__ gq, const float* __restrict__ betaq,
    const float* __restrict__ gk, const float* __restrict__ betak,
    const float* __restrict__ gv, const float* __restrict__ betav,
    short* __restrict__ pq, short* __restrict__ pk, short* __restrict__ pv)
{
    int wid  = threadIdx.x >> 6;
    int lane = threadIdx.x & 63;
    int gid  = blockIdx.x * 4 + wid;           // 64 * 1008 slots exactly
    int b = gid / 1008;
    int t = gid % 1008;
    bool act = (lane < 48);
    int c = lane * 2;                          // channels c, c+1
    const long hb = (long)b * NTOT * CIN;

    if (t < NQP) {                              // ---- q path (stride 2) ----
        short* outp = pq + ((long)b*NQP + t)*CIN;
        if (t >= NQ) { if (act) *reinterpret_cast<unsigned*>(outp + c) = 0u; return; }
        float xa = 0.f, xb = 0.f;
        if (t == 0) {
            if (act) { float2 h2 = *reinterpret_cast<const float2*>(hs + hb + c); xa = h2.x; xb = h2.y; }
        } else {
            int j = t - 1, oy = j / QW, ox = j % QW;
            #pragma unroll
            for (int dy = 0; dy < 3; ++dy) {
                int iy = oy*2 - 1 + dy;
                if (iy < 0 || iy >= HFS) continue;
                #pragma unroll
                for (int dx = 0; dx < 3; ++dx) {
                    int ix = ox*2 - 1 + dx;
                    if (ix < 0 || ix >= HFS) continue;
                    if (act) {
                        long base = hb + (long)(1 + iy*HFS + ix) * CIN;
                        float2 h2 = *reinterpret_cast<const float2*>(hs + base + c);
                        float2 w2 = *reinterpret_cast<const float2*>(cwqT + (dy*3+dx)*96 + c);
                        xa = fmaf(h2.x, w2.x, xa);
                        xb = fmaf(h2.y, w2.y, xb);
                    }
                }
            }
        }
        ln_store2(xa, xb, act, gq, betaq, outp, c);
    } else {                                    // ---- k+v fused (stride 4) ----
        int tok = t - NQP;
        short* ok_ = pk + ((long)b*NKP + tok)*CIN;
        short* ov_ = pv + ((long)b*NKP + tok)*CIN;
        if (tok >= NK) {
            if (act) {
                *reinterpret_cast<unsigned*>(ok_ + c) = 0u;
                *reinterpret_cast<unsigned*>(ov_ + c) = 0u;
            }
            return;
        }
        float ka = 0.f, kb_ = 0.f, va = 0.f, vb = 0.f;
        if (tok == 0) {
            if (act) {
                float2 h2 = *reinterpret_cast<const float2*>(hs + hb + c);
                ka = va = h2.x;  kb_ = vb = h2.y;
            }
        } else {
            int j = tok - 1, oy = j / KW, ox = j % KW;
            #pragma unroll
            for (int dy = 0; dy < 3; ++dy) {
                int iy = oy*4 - 1 + dy;
                if (iy < 0 || iy >= HFS) continue;
                #pragma unroll
                for (int dx = 0; dx < 3; ++dx) {
                    int ix = ox*4 - 1 + dx;
                    if (ix < 0 || ix >= HFS) continue;
                    if (act) {
                        long base = hb + (long)(1 + iy*HFS + ix) * CIN;
                        int wo = (dy*3+dx)*96 + c;
                        float2 h2 = *reinterpret_cast<const float2*>(hs + base + c);
                        float2 wk2 = *reinterpret_cast<const float2*>(cwkT + wo);
                        float2 wv2 = *reinterpret_cast<const float2*>(cwvT + wo);
                        ka  = fmaf(h2.x, wk2.x, ka);
                        kb_ = fmaf(h2.y, wk2.y, kb_);
                        va  = fmaf(h2.x, wv2.x, va);
                        vb  = fmaf(h2.y, wv2.y, vb);
                    }
                }
            }
        }
        ln_store2(ka, kb_, act, gk, betak, ok_, c);
        ln_store2(va, vb, act, gv, betav, ov_, c);
    }
}

// ---------------------------------------------------------------------------
// Kernel 2: projections as MFMA GEMM. One wave per 16-token tile.
// q/k: swapped orientation (A=W^T rows, B=token rows) -> lane holds 4
//      consecutive output channels for one token -> packed 8-B stores.
// v:   original orientation -> lane holds 4 consecutive tokens at one
//      channel -> packed 8-B stores into transposed vt.
// ---------------------------------------------------------------------------
__global__ __launch_bounds__(256) void proj_mfma_kernel(
    const short* __restrict__ pq, const short* __restrict__ pk, const short* __restrict__ pv,
    const short* __restrict__ WTq, const short* __restrict__ WTk, const short* __restrict__ WTv,
    const float* __restrict__ bq, const float* __restrict__ bk, const float* __restrict__ bv,
    short* __restrict__ qb, short* __restrict__ kb, short* __restrict__ vt)
{
    int wid  = threadIdx.x >> 6;
    int lane = threadIdx.x & 63;
    int quad = lane >> 4, col = lane & 15;
    int wt = blockIdx.x * 4 + wid;              // 4864 tiles total

    if (wt < 4032) {                            // ---- q and k: swapped ----
        const short *A, *WT; const float* bias; short* outp;
        int ntokp, row0; float bsc;
        if (wt < 3200) { A = pq; WT = WTq; bias = bq; outp = qb; ntokp = NQP; row0 = wt*16; bsc = 1.f; }
        else           { A = pk; WT = WTk; bias = bk; outp = kb; ntokp = NKP; row0 = (wt-3200)*16; bsc = KSCL; }

        short8 bt[3];
        #pragma unroll
        for (int cc = 0; cc < 3; ++cc)
            bt[cc] = ld8(A + (long)(row0 + col)*96 + cc*32 + quad*8);

        int b = row0 / ntokp;
        int tok = (row0 % ntokp) + col;

        #pragma unroll
        for (int nt = 0; nt < 12; ++nt) {
            floatx4 acc = {0.f, 0.f, 0.f, 0.f};
            #pragma unroll
            for (int cc = 0; cc < 3; ++cc) {
                short8 af = ld8(WT + (nt*16 + col)*96 + cc*32 + quad*8);
                acc = MFMA16(af, bt[cc], acc);
            }
            int o0 = nt*16 + quad*4;            // 4 consecutive outputs
            float4 bo = *reinterpret_cast<const float4*>(bias + o0);
            int h  = (o0 >= 96) ? 1 : 0;
            int d0 = o0 - h*96;
            shortx4 val;
            val.x = f2s(acc[0] + bo.x*bsc);
            val.y = f2s(acc[1] + bo.y*bsc);
            val.z = f2s(acc[2] + bo.z*bsc);
            val.w = f2s(acc[3] + bo.w*bsc);
            *reinterpret_cast<shortx4*>(outp + ((long)(b*2 + h)*ntokp + tok)*96 + d0) = val;
        }
    } else {                                    // ---- v: original orient ----
        int row0 = (wt - 4032) * 16;
        short8 at[3];
        #pragma unroll
        for (int cc = 0; cc < 3; ++cc)
            at[cc] = ld8(pv + (long)(row0 + col)*96 + cc*32 + quad*8);

        int b = row0 / NKP;
        int tloc0 = (row0 % NKP) + quad*4;      // 4 consecutive tokens

        #pragma unroll
        for (int nt = 0; nt < 12; ++nt) {
            floatx4 acc = {0.f, 0.f, 0.f, 0.f};
            #pragma unroll
            for (int cc = 0; cc < 3; ++cc) {
                short8 bf = ld8(WTv + (nt*16 + col)*96 + cc*32 + quad*8);
                acc = MFMA16(at[cc], bf, acc);
            }
            int o = nt*16 + col;
            int h = (o >= 96) ? 1 : 0;
            int d = o - h*96;
            float bo = bv[o];
            shortx4 val;
            val.x = (tloc0+0 < NK) ? f2s(acc[0] + bo) : (short)0;
            val.y = (tloc0+1 < NK) ? f2s(acc[1] + bo) : (short)0;
            val.z = (tloc0+2 < NK) ? f2s(acc[2] + bo) : (short)0;
            val.w = (tloc0+3 < NK) ? f2s(acc[3] + bo) : (short)0;
            *reinterpret_cast<shortx4*>(vt + ((long)(b*2 + h)*VROWS + d)*NKPV + tloc0) = val;
        }
    }
}

// ---------------------------------------------------------------------------
// Kernel 3: MFMA attention, one wave per 16-q-row tile.
// E = Q Rel^T -> LDS (bf16). Fused S-MFMA + bias-gather + exp per k-tile
// (no max-sub: |s| < 1). Row sums via ones-row appended to V^T (7th n-tile).
// Epilogue: broadcast sum, *1/sum, +q residual. XCD-swizzled block order.
// ---------------------------------------------------------------------------
__global__ __launch_bounds__(256) void attn_kernel(
    const short* __restrict__ qb, const short* __restrict__ kb,
    const short* __restrict__ vt, const short* __restrict__ relc,
    float* __restrict__ out)
{
    __shared__ short e_s[4][16][112];                 // bf16 E (14 KB)
    __shared__ __align__(16) short p_s[4][16][232];   // bf16 P (29 KB)

    int tid  = threadIdx.x;
    int wid  = tid >> 6;
    int lane = tid & 63;
    int quad = lane >> 4, col = lane & 15;

    int bid = blockIdx.x;                      // 1600 = 8 * 200
    int tb  = (bid & 7) * 200 + (bid >> 3);    // XCD-contiguous tile ranges
    int wt  = tb * 4 + wid;
    int bh  = wt / 50;
    int t   = wt % 50;
    int q0  = t * 16;

    // Q A-fragments
    const short* qrow = qb + ((long)bh*NQP + q0)*96;
    short8 aq[3];
    #pragma unroll
    for (int c = 0; c < 3; ++c)
        aq[c] = ld8(qrow + col*96 + c*32 + quad*8);

    // E = Q Rel^T  (cols 0..53 = rel_h dots, 54..107 = rel_w dots)
    #pragma unroll
    for (int rt = 0; rt < 7; ++rt) {
        floatx4 acc = {0.f, 0.f, 0.f, 0.f};
        #pragma unroll
        for (int c = 0; c < 3; ++c) {
            short8 bf = ld8(relc + (rt*16 + col)*96 + c*32 + quad*8);
            acc = MFMA16(aq[c], bf, acc);
        }
        #pragma unroll
        for (int reg = 0; reg < 4; ++reg)
            e_s[wid][quad*4 + reg][rt*16 + col] = f2s(acc[reg]);
    }

    // per-row q spatial coords
    int qyo[4], qxo[4];
    #pragma unroll
    for (int reg = 0; reg < 4; ++reg) {
        int qq = q0 + quad*4 + reg;
        int jj = (qq > 0) ? (qq - 1) : 0;
        qyo[reg] = jj / QW;
        qxo[reg] = jj % QW;
    }

    // fused S = Q K^T (scale pre-folded) + rel bias + exp -> P (bf16 LDS)
    const short* kbase = kb + (long)bh*NKP*96;
    #pragma unroll
    for (int kt = 0; kt < 13; ++kt) {
        floatx4 acc = {0.f, 0.f, 0.f, 0.f};
        #pragma unroll
        for (int c = 0; c < 3; ++c) {
            short8 bf = ld8(kbase + (kt*16 + col)*96 + c*32 + quad*8);
            acc = MFMA16(aq[c], bf, acc);
        }
        int k  = kt*16 + col;
        int kk = (k > 0) ? (k - 1) : 0;
        int ky = kk / 14;  ky = (ky < 13) ? ky : 13;
        int kx = kk - 14*ky;
        int oh = 26 - 2*ky;
        int ow2 = 26 - 2*kx;
        #pragma unroll
        for (int reg = 0; reg < 4; ++reg) {
            const short* er = &e_s[wid][quad*4 + reg][0];
            float bias = s2f(er[qyo[reg] + oh]) + s2f(er[54 + qxo[reg] + ow2]);
            if (kt == 0) bias = (col == 0) ? 0.f : bias;              // CLS col
            if (q0 == 0 && reg == 0) bias = (quad == 0) ? 0.f : bias; // CLS row
            p_s[wid][quad*4 + reg][k] = f2s(__expf(acc[reg] + bias));
        }
    }
    #pragma unroll
    for (int reg = 0; reg < 4; ++reg)          // zero PV pad cols 208..223
        p_s[wid][quad*4 + reg][208 + col] = 0;

    // O = P V  (7 K-chunks of 32; 6 V n-tiles + 1 ones-row n-tile = row sums)
    floatx4 o[7];
    #pragma unroll
    for (int nt = 0; nt < 7; ++nt) o[nt] = floatx4{0.f, 0.f, 0.f, 0.f};
    const short* vbase = vt + (long)bh*VROWS*NKPV;
    #pragma unroll
    for (int c = 0; c < 7; ++c) {
        short8 ap = ld8(&p_s[wid][col][c*32 + quad*8]);
        #pragma unroll
        for (int nt = 0; nt < 7; ++nt) {
            short8 bf = ld8(vbase + (nt*16 + col)*NKPV + c*32 + quad*8);
            o[nt] = MFMA16(ap, bf, o[nt]);
        }
    }

    // epilogue: broadcast row sum (col 0 of n-tile 6), normalize, +residual
    float inv[4];
    #pragma unroll
    for (int reg = 0; reg < 4; ++reg) {
        float srow = __shfl(o[6][reg], lane & 48, 64);
        inv[reg] = 1.0f / srow;
    }
    int b = bh >> 1, h = bh & 1;
    #pragma unroll
    for (int nt = 0; nt < 6; ++nt) {
        int ch = nt*16 + col;
        #pragma unroll
        for (int reg = 0; reg < 4; ++reg) {
            int q = q0 + quad*4 + reg;
            if (q < NQ) {
                float val = o[nt][reg] * inv[reg];
                if (q > 0) val += s2f(qb[((long)bh*NQP + q)*96 + ch]);
                out[((long)b*NQ + q)*192 + h*96 + ch] = val;
            }
        }
    }
}

// ---------------------------------------------------------------------------
extern "C" void kernel_launch(void* const* d_in, const int* in_sizes, int n_in,
                              void* d_out, int out_size, void* d_ws, size_t ws_size,
                              hipStream_t stream)
{
    const float* hs    = (const float*)d_in[0];
    const float* Wq    = (const float*)d_in[1];
    const float* bq    = (const float*)d_in[2];
    const float* Wk    = (const float*)d_in[3];
    const float* bk    = (const float*)d_in[4];
    const float* Wv    = (const float*)d_in[5];
    const float* bv    = (const float*)d_in[6];
    const float* pqw   = (const float*)d_in[7];
    const float* pkw   = (const float*)d_in[8];
    const float* pvw   = (const float*)d_in[9];
    const float* gq    = (const float*)d_in[10];
    const float* betaq = (const float*)d_in[11];
    const float* gk    = (const float*)d_in[12];
    const float* betak = (const float*)d_in[13];
    const float* gv    = (const float*)d_in[14];
    const float* betav = (const float*)d_in[15];
    const float* relh  = (const float*)d_in[16];
    const float* relw  = (const float*)d_in[17];
    float* out = (float*)d_out;

    // workspace carve (bf16 as short) — ~46.3 MB
    short* pq   = (short*)d_ws;                  // [64][800][96]
    short* pk   = pq  + (long)B_*NQP*CIN;        // [64][208][96]
    short* pv   = pk  + (long)B_*NKP*CIN;        // [64][208][96]
    short* qb   = pv  + (long)B_*NKP*CIN;        // [128][800][96]
    short* kb   = qb  + (long)128*NQP*96;        // [128][208][96]
    short* vt   = kb  + (long)128*NKP*96;        // [128][112][224]
    short* WTq  = vt  + (long)128*VROWS*NKPV;    // [192][96]
    short* WTk  = WTq + 192*96;
    short* WTv  = WTk + 192*96;
    short* relc = WTv + 192*96;                  // [112][96]
    float* cwqT = (float*)(relc + 112*96);       // [9][96] fp32
    float* cwkT = cwqT + 9*96;
    float* cwvT = cwkT + 9*96;

    prep_kernel<<<2829, 256, 0, stream>>>(Wq, Wk, Wv, relh, relw,
                                          pqw, pkw, pvw,
                                          WTq, WTk, WTv, relc, vt,
                                          cwqT, cwkT, cwvT);

    pool_ln_kernel<<<(B_*1008)/4, 256, 0, stream>>>(
        hs, cwqT, cwkT, cwvT, gq, betaq, gk, betak, gv, betav, pq, pk, pv);

    proj_mfma_kernel<<<4864/4, 256, 0, stream>>>(
        pq, pk, pv, WTq, WTk, WTv, bq, bk, bv, qb, kb, vt);

    attn_kernel<<<1600, 256, 0, stream>>>(qb, kb, vt, relc, out);
}